// Round 12
// baseline (488.310 us; speedup 1.0000x reference)
//
#include <hip/hip_runtime.h>
#include <cstdint>

typedef unsigned short u16;
typedef u16 u16x8 __attribute__((ext_vector_type(8)));
typedef __bf16 bf16x8 __attribute__((ext_vector_type(8)));
typedef float f32x4 __attribute__((ext_vector_type(4)));

#define GLOAD_LDS16(g, l)                                                          \
  __builtin_amdgcn_global_load_lds((const __attribute__((address_space(1))) void*)(g), \
                                   (__attribute__((address_space(3))) void*)(l), 16, 0, 0)

#define BARRIER() do { asm volatile("" ::: "memory");                 \
                       __builtin_amdgcn_sched_barrier(0);             \
                       __builtin_amdgcn_s_barrier();                  \
                       __builtin_amdgcn_sched_barrier(0);             \
                       asm volatile("" ::: "memory"); } while (0)
#define VMCNT2() asm volatile("s_waitcnt vmcnt(2)" ::: "memory")
#define VMCNT0() asm volatile("s_waitcnt vmcnt(0)" ::: "memory")
#define LGKM0()  do { asm volatile("s_waitcnt lgkmcnt(0)" ::: "memory");  \
                      __builtin_amdgcn_sched_barrier(0); } while (0)

__device__ __forceinline__ u16 f2bf(float f) {
  union { float f; uint32_t u; } v; v.f = f;
  uint32_t u = v.u;
  return (u16)((u + 0x7fffu + ((u >> 16) & 1u)) >> 16);  // RNE
}

constexpr long MH = 67108864L;    // 16384*4096
constexpr long MV = 8388608L;     // 2048*4096
constexpr long MU = 262144L;      // 32*128*64
constexpr long ML = 33554432L;    // 16384*2048

// ---------------- f32 -> bf16 pass over {VT, U} only (H is fused into the GEMM) ----------------
__global__ __launch_bounds__(256) void cvt_vu(const float* __restrict__ VT,
                                              const float* __restrict__ Uw,
                                              u16* __restrict__ dst) {
  const long n8 = (MV + MU) / 8;
  long i = (long)blockIdx.x * blockDim.x + threadIdx.x;
  long stride = (long)gridDim.x * blockDim.x;
  for (; i < n8; i += stride) {
    long j = i * 8;
    const float* src = (j < MV) ? (VT + j) : (Uw + (j - MV));
    const float4* p = (const float4*)src;
    float4 a = p[0], b = p[1];
    u16x8 o;
    o[0] = f2bf(a.x); o[1] = f2bf(a.y); o[2] = f2bf(a.z); o[3] = f2bf(a.w);
    o[4] = f2bf(b.x); o[5] = f2bf(b.y); o[6] = f2bf(b.z); o[7] = f2bf(b.w);
    *(u16x8*)(dst + j) = o;
  }
}

// ============ Fused: latents = H(f32) @ VT^T (256x256, BK=64, 8-phase) + U proj ============
constexpr int GK = 4096;
constexpr int NKT = GK / 64;   // 64 K-tiles

__device__ __forceinline__ void stage_half(u16* sm, const u16* g, int ldsbase, int w) {
  u16* l0 = sm + ldsbase + w * 1024;
  GLOAD_LDS16(g, l0);
  GLOAD_LDS16(g + 8 * GK, l0 + 512);
}

// A staging from f32: 4 dwordx4 loads (pre-swizzled source, same addressing as gload_lds)
__device__ __forceinline__ void loadA(const float* g, float4* r) {
  r[0] = *(const float4*)(g);
  r[1] = *(const float4*)(g + 4);
  r[2] = *(const float4*)(g + 8 * GK);
  r[3] = *(const float4*)(g + 8 * GK + 4);
}
// cvt + linear ds_write (identical dest layout to gload_lds: base + w*1024 + l*8, +512)
__device__ __forceinline__ void cvtWriteA(u16* sm, int ldsbase, int wl8, const float4* r) {
  u16x8 o0, o1;
  o0[0] = f2bf(r[0].x); o0[1] = f2bf(r[0].y); o0[2] = f2bf(r[0].z); o0[3] = f2bf(r[0].w);
  o0[4] = f2bf(r[1].x); o0[5] = f2bf(r[1].y); o0[6] = f2bf(r[1].z); o0[7] = f2bf(r[1].w);
  o1[0] = f2bf(r[2].x); o1[1] = f2bf(r[2].y); o1[2] = f2bf(r[2].z); o1[3] = f2bf(r[2].w);
  o1[4] = f2bf(r[3].x); o1[5] = f2bf(r[3].y); o1[6] = f2bf(r[3].z); o1[7] = f2bf(r[3].w);
  *(u16x8*)(sm + ldsbase + wl8) = o0;
  *(u16x8*)(sm + ldsbase + wl8 + 512) = o1;
}

__device__ __forceinline__ void readA(const u16* sm, int base, int msub, bf16x8* fA) {
#pragma unroll
  for (int mf = 0; mf < 4; ++mf) {
    int idx = base + (msub * 64 + mf * 16) * 64;
    fA[mf * 2]     = *(const bf16x8*)(sm + idx);
    fA[mf * 2 + 1] = *(const bf16x8*)(sm + (idx ^ 32));   // ks=1: k-slot +4 (XOR bit5)
  }
}

__device__ __forceinline__ void readB(const u16* sm, int base, int qn, bf16x8* fB) {
#pragma unroll
  for (int nf = 0; nf < 2; ++nf) {
    int idx = base + (qn * 32 + nf * 16) * 64;
    fB[nf * 2]     = *(const bf16x8*)(sm + idx);
    fB[nf * 2 + 1] = *(const bf16x8*)(sm + (idx ^ 32));
  }
}

__device__ __forceinline__ void mfma8(const bf16x8* fA, const bf16x8* fB,
                                      f32x4 (*acc)[4], int mbase, int nbase) {
  __builtin_amdgcn_s_setprio(1);
#pragma unroll
  for (int mf = 0; mf < 4; ++mf)
#pragma unroll
    for (int nf = 0; nf < 2; ++nf) {
      acc[mbase + mf][nbase + nf] = __builtin_amdgcn_mfma_f32_16x16x32_bf16(
          fA[mf * 2], fB[nf * 2], acc[mbase + mf][nbase + nf], 0, 0, 0);
      acc[mbase + mf][nbase + nf] = __builtin_amdgcn_mfma_f32_16x16x32_bf16(
          fA[mf * 2 + 1], fB[nf * 2 + 1], acc[mbase + mf][nbase + nf], 0, 0, 0);
    }
  __builtin_amdgcn_s_setprio(0);
}

// One iteration = 2 K-tiles (2i -> buf0, 2i+1 -> buf1), 8 phases, R8 barrier skeleton.
// B staged via gload_lds; A staged from f32: loads in odd phases (A first, then B
// gloads), {VMCNT2 -> cvt -> ds_write -> LGKM0} in the following even phase.
// vmcnt ledger (in-order retirement; 2 loads/B-stage, 4/A-batch):
//   entry: 2 outstanding (B0(o) from prev ph7)
//   ph1: +A_o.h0(4) +B1(o)(2)    ph2: VMCNT2 -> leaves B1(o); write buf1-A.h0
//   ph3: +A_o.h1(4) +B0(e2)(2)   ph4: VMCNT2 -> leaves B0(e2) [B1(o) landed for ph5]
//   ph5: +A_e2.h0(4) +B1(e2)(2)  ph6: VMCNT2 -> leaves B1(e2); write buf0-A.h0
//   ph7: +A_e2.h1(4) +B0(o2)(2)  ph8: VMCNT2 -> leaves B0(o2) [B1(e2) landed for ph1']
// A-write publishing: write + LGKM0 precede the phase-end barrier; first reader is
// >=1 barrier later (h0@ph2 -> read ph5; h1@ph4 -> ph5/ph7; buf0 h0@ph6,h1@ph8 -> ph1').
template <bool MORE>
__device__ __forceinline__ void kiter(u16* sm, int i, int w, int wl8,
                                      const float* gAf, const u16* gBs,
                                      int Ab0, int Bb0, bf16x8* fA, bf16x8* fB0,
                                      bf16x8* fB1, f32x4 (*acc)[4]) {
  const long dOdd = (long)(2 * i + 1) * 64;
  const long dE2  = (long)(2 * i + 2) * 64;
  const long dO3  = (long)(2 * i + 3) * 64;
  const long hOffB = 128L * GK;
  const long hOffA = 128L * GK;
  float4 rA[4];

  // ph1: reads buf0 {B n0, A m0}; load A_o half0 (f32); stage B1(o); MFMA q(m0,n0)
  readB(sm, Bb0, 0, fB0);
  readA(sm, Ab0, 0, fA);
  loadA(gAf + dOdd, rA);
  stage_half(sm, gBs + hOffB + dOdd, 32768 + 24576, w);
  BARRIER();
  mfma8(fA, fB0, acc, 0, 0);
  BARRIER();
  // ph2: read B(n1) buf0; VMCNT2; cvt+write buf1-A half0; LGKM0; MFMA q(m0,n1)
  readB(sm, Bb0, 1, fB1);
  VMCNT2();
  cvtWriteA(sm, 16384, wl8, rA);
  LGKM0();
  BARRIER();
  mfma8(fA, fB1, acc, 0, 2);
  BARRIER();
  // ph3: read A(m1) buf0; load A_o half1; stage B0(e+2); MFMA q(m1,n1)
  readA(sm, Ab0, 1, fA);
  loadA(gAf + hOffA + dOdd, rA);
  if constexpr (MORE) stage_half(sm, gBs + dE2, 32768, w);
  BARRIER();
  mfma8(fA, fB1, acc, 4, 2);
  BARRIER();
  // ph4: VMCNT (A_o.h1 done + B1(o) landed); cvt+write buf1-A half1; LGKM0; MFMA q(m1,n0)
  if constexpr (MORE) VMCNT2(); else VMCNT0();
  cvtWriteA(sm, 24576, wl8, rA);
  LGKM0();
  BARRIER();
  mfma8(fA, fB0, acc, 4, 0);
  BARRIER();
  // ph5: reads buf1 {B n0, A m0}; load A_e2 half0; stage B1(e+2); MFMA q(m0,n0) o
  readB(sm, Bb0 + 16384, 0, fB0);
  readA(sm, Ab0 + 16384, 0, fA);
  if constexpr (MORE) {
    loadA(gAf + dE2, rA);
    stage_half(sm, gBs + hOffB + dE2, 32768 + 8192, w);
  }
  BARRIER();
  mfma8(fA, fB0, acc, 0, 0);
  BARRIER();
  // ph6: read B(n1) buf1; VMCNT2; cvt+write buf0-A half0; LGKM0; MFMA q(m0,n1) o
  readB(sm, Bb0 + 16384, 1, fB1);
  if constexpr (MORE) {
    VMCNT2();
    cvtWriteA(sm, 0, wl8, rA);
    LGKM0();
  }
  BARRIER();
  mfma8(fA, fB1, acc, 0, 2);
  BARRIER();
  // ph7: read A(m1) buf1; load A_e2 half1; stage B0(o+2); MFMA q(m1,n1) o
  readA(sm, Ab0 + 16384, 1, fA);
  if constexpr (MORE) {
    loadA(gAf + hOffA + dE2, rA);
    stage_half(sm, gBs + dO3, 32768 + 16384, w);
  }
  BARRIER();
  mfma8(fA, fB1, acc, 4, 2);
  BARRIER();
  // ph8: VMCNT2 (A_e2.h1 done + B1(e+2) landed for ph1-next); cvt+write buf0-A half1;
  //      LGKM0; MFMA q(m1,n0) o
  if constexpr (MORE) {
    VMCNT2();
    cvtWriteA(sm, 8192, wl8, rA);
    LGKM0();
  } else {
    VMCNT0();
  }
  BARRIER();
  mfma8(fA, fB0, acc, 4, 0);
  BARRIER();
}

__global__ __launch_bounds__(512, 2) void gemm256_fused(const float* __restrict__ A,
                                                        const u16* __restrict__ B,
                                                        const u16* __restrict__ Ubf,
                                                        const float* __restrict__ Ubias,
                                                        float* __restrict__ out) {
  // LDS: K-loop ring uses [0, 65536); epilogue lat tile [256][260] uses [0, 66560)
  __shared__ u16 sm[66560];
  int bid = blockIdx.x;               // 512 blocks, 512 % 8 == 0 -> bijective XCD swizzle
  int swz = (bid & 7) * 64 + (bid >> 3);
  int tn = swz & 7;
  int tm = swz >> 3;
  int t0 = threadIdx.x;
  int w = t0 >> 6, l = t0 & 63;
  int wr = w >> 2, wc = w & 3;        // 2 M-waves x 4 N-waves; per-wave 128x64 latents
  int lo = l & 15, hi = l >> 4;

  // staging source (pre-swizzled: LDS slot s of row r holds global k-slot s ^ (r&7))
  int lr = l >> 3;
  int sslot = (l & 7) ^ lr;
  const float* gAf = A + (long)(tm * 256 + w * 16 + lr) * GK + sslot * 8;
  const u16*   gBs = B + (long)(tn * 256 + w * 16 + lr) * GK + sslot * 8;
  int wl8 = w * 1024 + l * 8;         // linear LDS dest (u16), same as gload_lds

  // ds_read bases (u16): row-in-half = <sub>*16 + lo, 64 u16/row; slot = kslot ^ (lo&7)
  int slotbase = (hi ^ (lo & 7)) * 8;
  int Ab0 = wr * 8192 + lo * 64 + slotbase;
  int Bb0 = 32768 + (wc >> 1) * 8192 + ((wc & 1) * 64 + lo) * 64 + slotbase;

  bf16x8 fA[8], fB0[4], fB1[4];
  f32x4 acc[8][4] = {};

  // prologue: A(0) f32 loads (8) -> cvt -> buf0; B0(0),B1(0),B0(1) gload;
  // invariant at loop entry: 2 outstanding (B0(1)); tile0 fully in LDS.
  {
    float4 r0[4], r1[4];
    loadA(gAf, r0);
    loadA(gAf + 128L * GK, r1);
    stage_half(sm, gBs,             32768,         w);   // B0(0)
    stage_half(sm, gBs + 128L * GK, 32768 + 8192,  w);   // B1(0)
    stage_half(sm, gBs + 64,        32768 + 16384, w);   // B0(1)
    asm volatile("s_waitcnt vmcnt(6)" ::: "memory");     // A(0) landed
    cvtWriteA(sm, 0,    wl8, r0);
    cvtWriteA(sm, 8192, wl8, r1);
    VMCNT2();                                            // B0(0),B1(0) landed
    LGKM0();
    BARRIER();
  }

  for (int i = 0; i < NKT / 2 - 1; ++i)
    kiter<true>(sm, i, w, wl8, gAf, gBs, Ab0, Bb0, fA, fB0, fB1, acc);
  kiter<false>(sm, NKT / 2 - 1, w, wl8, gAf, gBs, Ab0, Bb0, fA, fB0, fB1, acc);

  // ================= fused stage-2 epilogue (wave-local) =================
  // Wave (wr,wc) owns lat rows [wr*128,+128) x cols [wc*64,+64) = group tn*4+wc.
  int g_abs = tn * 4 + wc;
#pragma unroll
  for (int mq = 0; mq < 8; ++mq)
#pragma unroll
    for (int n = 0; n < 4; ++n) {
      int rl = wr * 128 + mq * 16 + hi * 4;
      int cl = wc * 64 + n * 16 + lo;
#pragma unroll
      for (int j = 0; j < 4; ++j)
        sm[(rl + j) * 260 + cl] = f2bf(acc[mq][n][j]);
    }
  // per-wave ds_write -> ds_read ordering enforced by compiler lgkmcnt tracking
  const u16* Ug = Ubf + g_abs * 8192;        // [128][64] bf16, K-contiguous
#pragma unroll
  for (int mh = 0; mh < 2; ++mh) {
    bf16x8 fL[8];
#pragma unroll
    for (int ms = 0; ms < 4; ++ms) {
      int rl = wr * 128 + mh * 64 + ms * 16 + lo;
#pragma unroll
      for (int ks = 0; ks < 2; ++ks)
        fL[ms * 2 + ks] = *(const bf16x8*)(sm + rl * 260 + wc * 64 + ks * 32 + hi * 8);
    }
#pragma unroll
    for (int nf = 0; nf < 8; ++nf) {
      int d = nf * 16 + lo;
      bf16x8 u0 = *(const bf16x8*)(Ug + d * 64 + hi * 8);
      bf16x8 u1 = *(const bf16x8*)(Ug + d * 64 + 32 + hi * 8);
      float bias = Ubias[g_abs * 128 + d];
#pragma unroll
      for (int ms = 0; ms < 4; ++ms) {
        f32x4 o = {};
        o = __builtin_amdgcn_mfma_f32_16x16x32_bf16(fL[ms * 2],     u0, o, 0, 0, 0);
        o = __builtin_amdgcn_mfma_f32_16x16x32_bf16(fL[ms * 2 + 1], u1, o, 0, 0, 0);
        long row = (long)tm * 256 + wr * 128 + mh * 64 + ms * 16 + hi * 4;
        int col = g_abs * 128 + d;
#pragma unroll
        for (int j = 0; j < 4; ++j)
          out[(row + j) * 4096 + col] = o[j] + bias;
      }
    }
  }
}

// ============ Fallback (small ws): 128x128 m97-style, A converted in-kernel ============
__global__ __launch_bounds__(256) void gemm1_f32(const float* __restrict__ fAp,
                                                 const u16* __restrict__ B,
                                                 u16* __restrict__ Cl) {
  constexpr int K = 4096;
  __shared__ u16 sA[128 * 32];
  __shared__ u16 sB[128 * 32];
  int bid = blockIdx.x;
  int swz = (bid & 7) * 256 + (bid >> 3);
  int tn = swz & 15;
  int tm = swz >> 4;
  int t = threadIdx.x;
  int w = t >> 6, l = t & 63;
  int wr = w >> 1, wc = w & 1;
  int lo = l & 15, hi = l >> 4;
  const int rS = w * 32 + (l >> 2);
  const int kS = (l & 3) * 8;
  const u16* gB = B + (long)(tn * 128 + rS) * K + kS;
  u16* lB = &sB[w * 1024];
  int fr = t >> 1, fk = (t & 1) * 16;

  f32x4 acc[4][4] = {};
  for (int k0 = 0; k0 < K; k0 += 32) {
    const float* src = fAp + (long)(tm * 128 + fr) * K + k0 + fk;
    float4 x = *(const float4*)(src);
    float4 y = *(const float4*)(src + 4);
    float4 z = *(const float4*)(src + 8);
    float4 q = *(const float4*)(src + 12);
    u16x8 o1, o2;
    o1[0] = f2bf(x.x); o1[1] = f2bf(x.y); o1[2] = f2bf(x.z); o1[3] = f2bf(x.w);
    o1[4] = f2bf(y.x); o1[5] = f2bf(y.y); o1[6] = f2bf(y.z); o1[7] = f2bf(y.w);
    o2[0] = f2bf(z.x); o2[1] = f2bf(z.y); o2[2] = f2bf(z.z); o2[3] = f2bf(z.w);
    o2[4] = f2bf(q.x); o2[5] = f2bf(q.y); o2[6] = f2bf(q.z); o2[7] = f2bf(q.w);
    *(u16x8*)&sA[fr * 32 + fk] = o1;
    *(u16x8*)&sA[fr * 32 + fk + 8] = o2;
    GLOAD_LDS16(gB, lB);
    GLOAD_LDS16(gB + 16 * K, lB + 512);
    gB += 32;
    __syncthreads();
    bf16x8 af[4], bfr[4];
#pragma unroll
    for (int m = 0; m < 4; ++m)
      af[m] = *(const bf16x8*)&sA[(wr * 64 + m * 16 + lo) * 32 + hi * 8];
#pragma unroll
    for (int n = 0; n < 4; ++n)
      bfr[n] = *(const bf16x8*)&sB[(wc * 64 + n * 16 + lo) * 32 + hi * 8];
#pragma unroll
    for (int m = 0; m < 4; ++m)
#pragma unroll
      for (int n = 0; n < 4; ++n)
        acc[m][n] = __builtin_amdgcn_mfma_f32_16x16x32_bf16(af[m], bfr[n], acc[m][n], 0, 0, 0);
    __syncthreads();
  }
#pragma unroll
  for (int m = 0; m < 4; ++m)
#pragma unroll
    for (int n = 0; n < 4; ++n) {
      int col = tn * 128 + wc * 64 + n * 16 + lo;
      int row = tm * 128 + wr * 64 + m * 16 + hi * 4;
#pragma unroll
      for (int j = 0; j < 4; ++j)
        Cl[(long)(row + j) * 2048 + col] = f2bf(acc[m][n][j]);
    }
}

// ---------------- Fallback stage 2 ----------------
__global__ __launch_bounds__(256) void stage2(const u16* __restrict__ L,
                                              const u16* __restrict__ U,
                                              const float* __restrict__ Ub,
                                              float* __restrict__ out) {
  int tm = blockIdx.x, g = blockIdx.y;
  int t = threadIdx.x, w = t >> 6, l = t & 63;
  int lo = l & 15, hi = l >> 4;
  const u16* Lb = L + (long)(tm * 128 + w * 32) * 2048 + g * 64;
  const u16* Ug = U + g * 8192;
  f32x4 acc[2][8] = {};
#pragma unroll
  for (int ks = 0; ks < 2; ++ks) {
    int ek = ks * 32 + hi * 8;
    bf16x8 a0 = *(const bf16x8*)(Lb + (long)lo * 2048 + ek);
    bf16x8 a1 = *(const bf16x8*)(Lb + (long)(lo + 16) * 2048 + ek);
#pragma unroll
    for (int n = 0; n < 8; ++n) {
      bf16x8 bv = *(const bf16x8*)(Ug + (n * 16 + lo) * 64 + ek);
      acc[0][n] = __builtin_amdgcn_mfma_f32_16x16x32_bf16(a0, bv, acc[0][n], 0, 0, 0);
      acc[1][n] = __builtin_amdgcn_mfma_f32_16x16x32_bf16(a1, bv, acc[1][n], 0, 0, 0);
    }
  }
#pragma unroll
  for (int n = 0; n < 8; ++n) {
    int col = n * 16 + lo;
    float bias = Ub[g * 128 + col];
#pragma unroll
    for (int m = 0; m < 2; ++m) {
      int row = tm * 128 + w * 32 + m * 16 + hi * 4;
#pragma unroll
      for (int j = 0; j < 4; ++j)
        out[(long)(row + j) * 4096 + g * 128 + col] = acc[m][n][j] + bias;
    }
  }
}

extern "C" void kernel_launch(void* const* d_in, const int* in_sizes, int n_in,
                              void* d_out, int out_size, void* d_ws, size_t ws_size,
                              hipStream_t stream) {
  const float* H   = (const float*)d_in[0];   // [4,4096,4096]
  const float* VT  = (const float*)d_in[1];   // [2048,4096]
  const float* Uw  = (const float*)d_in[2];   // [32,128,64]
  const float* Ubp = (const float*)d_in[3];   // [32,128]
  float* out = (float*)d_out;                 // [4,4096,4096]
  size_t needFast = (size_t)(MV + MU) * 2;    // ~17.3 MB

  if (ws_size >= needFast && ws_size < (size_t)(MV + MU + ML) * 2) {
    u16* vbf = (u16*)d_ws;
    u16* ubf = vbf + MV;
    cvt_vu<<<512, 256, 0, stream>>>(VT, Uw, vbf);
    gemm256_fused<<<512, 512, 0, stream>>>(H, vbf, ubf, Ubp, out);
  } else if (ws_size >= (size_t)(MV + MU + ML) * 2) {
    // plenty of ws: still use the fused fast path (no lat buffer needed)
    u16* vbf = (u16*)d_ws;
    u16* ubf = vbf + MV;
    cvt_vu<<<512, 256, 0, stream>>>(VT, Uw, vbf);
    gemm256_fused<<<512, 512, 0, stream>>>(H, vbf, ubf, Ubp, out);
  } else {
    // extremely small ws fallback (needs MV+MU+lat)
    u16* vbf = (u16*)d_ws;
    u16* ubf = vbf + MV;
    u16* lat = ubf + MU;
    cvt_vu<<<512, 256, 0, stream>>>(VT, Uw, vbf);
    gemm1_f32<<<2048, 256, 0, stream>>>(H, vbf, lat);
    stage2<<<dim3(128, 32), 256, 0, stream>>>(lat, ubf, Ubp, out);
  }
}

// Round 13
// 348.988 us; speedup vs baseline: 1.3992x; 1.3992x over previous
//
#include <hip/hip_runtime.h>
#include <cstdint>

typedef unsigned short u16;
typedef u16 u16x8 __attribute__((ext_vector_type(8)));
typedef __bf16 bf16x8 __attribute__((ext_vector_type(8)));
typedef float f32x4 __attribute__((ext_vector_type(4)));

#define GLOAD_LDS16(g, l)                                                          \
  __builtin_amdgcn_global_load_lds((const __attribute__((address_space(1))) void*)(g), \
                                   (__attribute__((address_space(3))) void*)(l), 16, 0, 0)

#define BARRIER() do { asm volatile("" ::: "memory");                 \
                       __builtin_amdgcn_sched_barrier(0);             \
                       __builtin_amdgcn_s_barrier();                  \
                       __builtin_amdgcn_sched_barrier(0);             \
                       asm volatile("" ::: "memory"); } while (0)
#define VMCNT4() asm volatile("s_waitcnt vmcnt(4)" ::: "memory")
#define VMCNT0() asm volatile("s_waitcnt vmcnt(0)" ::: "memory")
#define LGKM8()  asm volatile("s_waitcnt lgkmcnt(8)" ::: "memory")

__device__ __forceinline__ u16 f2bf(float f) {
  union { float f; uint32_t u; } v; v.f = f;
  uint32_t u = v.u;
  return (u16)((u + 0x7fffu + ((u >> 16) & 1u)) >> 16);  // RNE
}

constexpr long MH = 67108864L;    // 16384*4096
constexpr long MV = 8388608L;     // 2048*4096
constexpr long MU = 262144L;      // 32*128*64
constexpr long ML = 33554432L;    // 16384*2048

// ---------------- single f32 -> bf16 pass over {H, VT, U} (contiguous dst) ----------------
__global__ __launch_bounds__(256) void cvt_all(const float* __restrict__ H,
                                               const float* __restrict__ VT,
                                               const float* __restrict__ Uw,
                                               u16* __restrict__ dst) {
  const long n8 = (MH + MV + MU) / 8;
  long i = (long)blockIdx.x * blockDim.x + threadIdx.x;
  long stride = (long)gridDim.x * blockDim.x;
  for (; i < n8; i += stride) {
    long j = i * 8;
    const float* src;
    if (j < MH)            src = H + j;
    else if (j < MH + MV)  src = VT + (j - MH);
    else                   src = Uw + (j - MH - MV);
    const float4* p = (const float4*)src;
    float4 a = p[0], b = p[1];
    u16x8 o;
    o[0] = f2bf(a.x); o[1] = f2bf(a.y); o[2] = f2bf(a.z); o[3] = f2bf(a.w);
    o[4] = f2bf(b.x); o[5] = f2bf(b.y); o[6] = f2bf(b.z); o[7] = f2bf(b.w);
    *(u16x8*)(dst + j) = o;
  }
}

// ============ Fused: latents = H @ VT^T (256x256, BK=64, 8-phase, 16x16x32) + U proj ============
constexpr int GK = 4096;
constexpr int NKT = GK / 64;   // 64 K-tiles

__device__ __forceinline__ void stage_half(u16* sm, const u16* g, int ldsbase, int w) {
  u16* l0 = sm + ldsbase + w * 1024;
  GLOAD_LDS16(g, l0);
  GLOAD_LDS16(g + 8 * GK, l0 + 512);
}

__device__ __forceinline__ void readA(const u16* sm, int base, int msub, bf16x8* fA) {
#pragma unroll
  for (int mf = 0; mf < 4; ++mf) {
    int idx = base + (msub * 64 + mf * 16) * 64;
    fA[mf * 2]     = *(const bf16x8*)(sm + idx);
    fA[mf * 2 + 1] = *(const bf16x8*)(sm + (idx ^ 32));   // ks=1: k-slot +4 (XOR bit5)
  }
}

__device__ __forceinline__ void readB(const u16* sm, int base, int qn, bf16x8* fB) {
#pragma unroll
  for (int nf = 0; nf < 2; ++nf) {
    int idx = base + (qn * 32 + nf * 16) * 64;
    fB[nf * 2]     = *(const bf16x8*)(sm + idx);
    fB[nf * 2 + 1] = *(const bf16x8*)(sm + (idx ^ 32));
  }
}

__device__ __forceinline__ void mfma8(const bf16x8* fA, const bf16x8* fB,
                                      f32x4 (*acc)[4], int mbase, int nbase) {
  __builtin_amdgcn_s_setprio(1);
#pragma unroll
  for (int mf = 0; mf < 4; ++mf)
#pragma unroll
    for (int nf = 0; nf < 2; ++nf) {
      acc[mbase + mf][nbase + nf] = __builtin_amdgcn_mfma_f32_16x16x32_bf16(
          fA[mf * 2], fB[nf * 2], acc[mbase + mf][nbase + nf], 0, 0, 0);
      acc[mbase + mf][nbase + nf] = __builtin_amdgcn_mfma_f32_16x16x32_bf16(
          fA[mf * 2 + 1], fB[nf * 2 + 1], acc[mbase + mf][nbase + nf], 0, 0, 0);
    }
  __builtin_amdgcn_s_setprio(0);
}

// One iteration = 2 K-tiles (2i -> buf0, 2i+1 -> buf1), 8 phases (ledger audited R4).
// R8 schedule: readB before readA in the 12-read phases; lgkmcnt(8) pre-barrier there.
template <bool MORE>
__device__ __forceinline__ void kiter(u16* sm, int i, int w,
                                      const u16* gAs, const u16* gBs,
                                      int Ab0, int Bb0, bf16x8* fA, bf16x8* fB0,
                                      bf16x8* fB1, f32x4 (*acc)[4]) {
  const long dOdd = (long)(2 * i + 1) * 64;
  const long dE2  = (long)(2 * i + 2) * 64;
  const long dO3  = (long)(2 * i + 3) * 64;
  const long hOff = 128L * GK;

  // ph1: read B(n0) then A(m0) from buf0; stage B1(2i+1)->buf1; partial lgkm drain
  readB(sm, Bb0, 0, fB0);
  readA(sm, Ab0, 0, fA);
  stage_half(sm, gBs + hOff + dOdd, 32768 + 24576, w);
  LGKM8();
  BARRIER();
  mfma8(fA, fB0, acc, 0, 0);
  BARRIER();
  // ph2: read B(n1) buf0; stage A1(2i+1)->buf1; MFMA q(m0,n1)
  readB(sm, Bb0, 1, fB1);
  stage_half(sm, gAs + hOff + dOdd, 24576, w);
  BARRIER();
  mfma8(fA, fB1, acc, 0, 2);
  BARRIER();
  // ph3: read A(m1) buf0; stage B0(2i+2)->buf0 (dead since ph2); MFMA q(m1,n1)
  readA(sm, Ab0, 1, fA);
  if constexpr (MORE) stage_half(sm, gBs + dE2, 32768, w);
  BARRIER();
  mfma8(fA, fB1, acc, 4, 2);
  BARRIER();
  // ph4: stage A0(2i+2)->buf0 (dead since ph3); counted vmcnt; MFMA q(m1,n0)
  if constexpr (MORE) stage_half(sm, gAs + dE2, 0, w);
  if constexpr (MORE) VMCNT4(); else VMCNT0();
  BARRIER();
  mfma8(fA, fB0, acc, 4, 0);
  BARRIER();
  // ph5: read B(n0) then A(m0) from buf1; stage B1(2i+2)->buf0; partial lgkm drain
  readB(sm, Bb0 + 16384, 0, fB0);
  readA(sm, Ab0 + 16384, 0, fA);
  if constexpr (MORE) stage_half(sm, gBs + hOff + dE2, 32768 + 8192, w);
  LGKM8();
  BARRIER();
  mfma8(fA, fB0, acc, 0, 0);
  BARRIER();
  // ph6: read B(n1) buf1; stage A1(2i+2)->buf0
  readB(sm, Bb0 + 16384, 1, fB1);
  if constexpr (MORE) stage_half(sm, gAs + hOff + dE2, 8192, w);
  BARRIER();
  mfma8(fA, fB1, acc, 0, 2);
  BARRIER();
  // ph7: read A(m1) buf1; stage B0(2i+3)->buf1 (dead since ph6)
  readA(sm, Ab0 + 16384, 1, fA);
  if constexpr (MORE) stage_half(sm, gBs + dO3, 32768 + 16384, w);
  BARRIER();
  mfma8(fA, fB1, acc, 4, 2);
  BARRIER();
  // ph8: stage A0(2i+3)->buf1 (dead since ph7); counted vmcnt; MFMA
  if constexpr (MORE) stage_half(sm, gAs + dO3, 16384, w);
  if constexpr (MORE) VMCNT4(); else VMCNT0();
  BARRIER();
  mfma8(fA, fB0, acc, 4, 0);
  BARRIER();
}

__global__ __launch_bounds__(512, 2) void gemm256_fused(const u16* __restrict__ A,
                                                        const u16* __restrict__ B,
                                                        const u16* __restrict__ Ubf,
                                                        const float* __restrict__ Ubias,
                                                        float* __restrict__ out) {
  // LDS: K-loop ring uses [0, 65536); epilogue lat tile [256][260] uses [0, 66560)
  __shared__ u16 sm[66560];
  int bid = blockIdx.x;               // 512 blocks, 512 % 8 == 0 -> bijective XCD swizzle
  int swz = (bid & 7) * 64 + (bid >> 3);
  int tn = swz & 7;
  int tm = swz >> 3;
  int t0 = threadIdx.x;
  int w = t0 >> 6, l = t0 & 63;
  int wr = w >> 2, wc = w & 3;        // 2 M-waves x 4 N-waves; per-wave 128x64 latents
  int lo = l & 15, hi = l >> 4;

  // staging source (pre-swizzled: LDS slot s of row r holds global k-slot s ^ (r&7))
  int lr = l >> 3;
  int sslot = (l & 7) ^ lr;
  const u16* gAs = A + (long)(tm * 256 + w * 16 + lr) * GK + sslot * 8;
  const u16* gBs = B + (long)(tn * 256 + w * 16 + lr) * GK + sslot * 8;

  // ds_read bases (u16): row-in-half = <sub>*16 + lo, 64 u16/row; slot = kslot ^ (lo&7)
  int slotbase = (hi ^ (lo & 7)) * 8;
  int Ab0 = wr * 8192 + lo * 64 + slotbase;
  int Bb0 = 32768 + (wc >> 1) * 8192 + ((wc & 1) * 64 + lo) * 64 + slotbase;

  bf16x8 fA[8], fB0[4], fB1[4];
  f32x4 acc[8][4] = {};

  // prologue: tile0 all 4 halves + tile1 {B0,A0}; vmcnt(4) -> tile0 landed
  stage_half(sm, gBs,               32768,         w);
  stage_half(sm, gAs,               0,             w);
  stage_half(sm, gBs + 128L * GK,   32768 + 8192,  w);
  stage_half(sm, gAs + 128L * GK,   8192,          w);
  stage_half(sm, gBs + 64,          32768 + 16384, w);
  stage_half(sm, gAs + 64,          16384,         w);
  VMCNT4();
  BARRIER();

  for (int i = 0; i < NKT / 2 - 1; ++i)
    kiter<true>(sm, i, w, gAs, gBs, Ab0, Bb0, fA, fB0, fB1, acc);
  kiter<false>(sm, NKT / 2 - 1, w, gAs, gBs, Ab0, Bb0, fA, fB0, fB1, acc);

  // ================= fused stage-2 epilogue (wave-local) =================
  // Wave (wr,wc) owns lat rows [wr*128,+128) x cols [wc*64,+64) = group tn*4+wc.
  int g_abs = tn * 4 + wc;
#pragma unroll
  for (int mq = 0; mq < 8; ++mq)
#pragma unroll
    for (int n = 0; n < 4; ++n) {
      int rl = wr * 128 + mq * 16 + hi * 4;
      int cl = wc * 64 + n * 16 + lo;
#pragma unroll
      for (int j = 0; j < 4; ++j)
        sm[(rl + j) * 260 + cl] = f2bf(acc[mq][n][j]);
    }
  // per-wave ds_write -> ds_read ordering enforced by compiler lgkmcnt tracking
  const u16* Ug = Ubf + g_abs * 8192;        // [128][64] bf16, K-contiguous
#pragma unroll
  for (int mh = 0; mh < 2; ++mh) {
    bf16x8 fL[8];
#pragma unroll
    for (int ms = 0; ms < 4; ++ms) {
      int rl = wr * 128 + mh * 64 + ms * 16 + lo;
#pragma unroll
      for (int ks = 0; ks < 2; ++ks)
        fL[ms * 2 + ks] = *(const bf16x8*)(sm + rl * 260 + wc * 64 + ks * 32 + hi * 8);
    }
#pragma unroll
    for (int nf = 0; nf < 8; ++nf) {
      int d = nf * 16 + lo;
      bf16x8 u0 = *(const bf16x8*)(Ug + d * 64 + hi * 8);
      bf16x8 u1 = *(const bf16x8*)(Ug + d * 64 + 32 + hi * 8);
      float bias = Ubias[g_abs * 128 + d];
#pragma unroll
      for (int ms = 0; ms < 4; ++ms) {
        f32x4 o = {};
        o = __builtin_amdgcn_mfma_f32_16x16x32_bf16(fL[ms * 2],     u0, o, 0, 0, 0);
        o = __builtin_amdgcn_mfma_f32_16x16x32_bf16(fL[ms * 2 + 1], u1, o, 0, 0, 0);
        long row = (long)tm * 256 + wr * 128 + mh * 64 + ms * 16 + hi * 4;
        int col = g_abs * 128 + d;
#pragma unroll
        for (int j = 0; j < 4; ++j)
          out[(row + j) * 4096 + col] = o[j] + bias;
      }
    }
  }
}

// ============ Fallback (small ws): 128x128 m97-style, A converted in-kernel ============
__global__ __launch_bounds__(256) void gemm1_f32(const float* __restrict__ fAp,
                                                 const u16* __restrict__ B,
                                                 u16* __restrict__ Cl) {
  constexpr int K = 4096;
  __shared__ u16 sA[128 * 32];
  __shared__ u16 sB[128 * 32];
  int bid = blockIdx.x;
  int swz = (bid & 7) * 256 + (bid >> 3);
  int tn = swz & 15;
  int tm = swz >> 4;
  int t = threadIdx.x;
  int w = t >> 6, l = t & 63;
  int wr = w >> 1, wc = w & 1;
  int lo = l & 15, hi = l >> 4;
  const int rS = w * 32 + (l >> 2);
  const int kS = (l & 3) * 8;
  const u16* gB = B + (long)(tn * 128 + rS) * K + kS;
  u16* lB = &sB[w * 1024];
  int fr = t >> 1, fk = (t & 1) * 16;

  f32x4 acc[4][4] = {};
  for (int k0 = 0; k0 < K; k0 += 32) {
    const float* src = fAp + (long)(tm * 128 + fr) * K + k0 + fk;
    float4 x = *(const float4*)(src);
    float4 y = *(const float4*)(src + 4);
    float4 z = *(const float4*)(src + 8);
    float4 q = *(const float4*)(src + 12);
    u16x8 o1, o2;
    o1[0] = f2bf(x.x); o1[1] = f2bf(x.y); o1[2] = f2bf(x.z); o1[3] = f2bf(x.w);
    o1[4] = f2bf(y.x); o1[5] = f2bf(y.y); o1[6] = f2bf(y.z); o1[7] = f2bf(y.w);
    o2[0] = f2bf(z.x); o2[1] = f2bf(z.y); o2[2] = f2bf(z.z); o2[3] = f2bf(z.w);
    o2[4] = f2bf(q.x); o2[5] = f2bf(q.y); o2[6] = f2bf(q.z); o2[7] = f2bf(q.w);
    *(u16x8*)&sA[fr * 32 + fk] = o1;
    *(u16x8*)&sA[fr * 32 + fk + 8] = o2;
    GLOAD_LDS16(gB, lB);
    GLOAD_LDS16(gB + 16 * K, lB + 512);
    gB += 32;
    __syncthreads();
    bf16x8 af[4], bfr[4];
#pragma unroll
    for (int m = 0; m < 4; ++m)
      af[m] = *(const bf16x8*)&sA[(wr * 64 + m * 16 + lo) * 32 + hi * 8];
#pragma unroll
    for (int n = 0; n < 4; ++n)
      bfr[n] = *(const bf16x8*)&sB[(wc * 64 + n * 16 + lo) * 32 + hi * 8];
#pragma unroll
    for (int m = 0; m < 4; ++m)
#pragma unroll
      for (int n = 0; n < 4; ++n)
        acc[m][n] = __builtin_amdgcn_mfma_f32_16x16x32_bf16(af[m], bfr[n], acc[m][n], 0, 0, 0);
    __syncthreads();
  }
#pragma unroll
  for (int m = 0; m < 4; ++m)
#pragma unroll
    for (int n = 0; n < 4; ++n) {
      int col = tn * 128 + wc * 64 + n * 16 + lo;
      int row = tm * 128 + wr * 64 + m * 16 + hi * 4;
#pragma unroll
      for (int j = 0; j < 4; ++j)
        Cl[(long)(row + j) * 2048 + col] = f2bf(acc[m][n][j]);
    }
}

// ---------------- Fallback stage 2 ----------------
__global__ __launch_bounds__(256) void stage2(const u16* __restrict__ L,
                                              const u16* __restrict__ U,
                                              const float* __restrict__ Ub,
                                              float* __restrict__ out) {
  int tm = blockIdx.x, g = blockIdx.y;
  int t = threadIdx.x, w = t >> 6, l = t & 63;
  int lo = l & 15, hi = l >> 4;
  const u16* Lb = L + (long)(tm * 128 + w * 32) * 2048 + g * 64;
  const u16* Ug = U + g * 8192;
  f32x4 acc[2][8] = {};
#pragma unroll
  for (int ks = 0; ks < 2; ++ks) {
    int ek = ks * 32 + hi * 8;
    bf16x8 a0 = *(const bf16x8*)(Lb + (long)lo * 2048 + ek);
    bf16x8 a1 = *(const bf16x8*)(Lb + (long)(lo + 16) * 2048 + ek);
#pragma unroll
    for (int n = 0; n < 8; ++n) {
      bf16x8 bv = *(const bf16x8*)(Ug + (n * 16 + lo) * 64 + ek);
      acc[0][n] = __builtin_amdgcn_mfma_f32_16x16x32_bf16(a0, bv, acc[0][n], 0, 0, 0);
      acc[1][n] = __builtin_amdgcn_mfma_f32_16x16x32_bf16(a1, bv, acc[1][n], 0, 0, 0);
    }
  }
#pragma unroll
  for (int n = 0; n < 8; ++n) {
    int col = n * 16 + lo;
    float bias = Ub[g * 128 + col];
#pragma unroll
    for (int m = 0; m < 2; ++m) {
      int row = tm * 128 + w * 32 + m * 16 + hi * 4;
#pragma unroll
      for (int j = 0; j < 4; ++j)
        out[(long)(row + j) * 4096 + g * 128 + col] = acc[m][n][j] + bias;
    }
  }
}

__global__ __launch_bounds__(256) void cvt_f32_bf16(const float* __restrict__ in,
                                                    u16* __restrict__ out, long n8) {
  long i = (long)blockIdx.x * blockDim.x + threadIdx.x;
  long stride = (long)gridDim.x * blockDim.x;
  for (; i < n8; i += stride) {
    const float4* p = (const float4*)(in + i * 8);
    float4 a = p[0], b = p[1];
    u16x8 o;
    o[0] = f2bf(a.x); o[1] = f2bf(a.y); o[2] = f2bf(a.z); o[3] = f2bf(a.w);
    o[4] = f2bf(b.x); o[5] = f2bf(b.y); o[6] = f2bf(b.z); o[7] = f2bf(b.w);
    *(u16x8*)(out + i * 8) = o;
  }
}

extern "C" void kernel_launch(void* const* d_in, const int* in_sizes, int n_in,
                              void* d_out, int out_size, void* d_ws, size_t ws_size,
                              hipStream_t stream) {
  const float* H   = (const float*)d_in[0];   // [4,4096,4096]
  const float* VT  = (const float*)d_in[1];   // [2048,4096]
  const float* Uw  = (const float*)d_in[2];   // [32,128,64]
  const float* Ubp = (const float*)d_in[3];   // [32,128]
  float* out = (float*)d_out;                 // [4,4096,4096]
  size_t needFull = (size_t)(MH + MV + MU) * 2;   // ~151.6 MB

  if (ws_size >= needFull) {
    u16* hbf = (u16*)d_ws;
    u16* vbf = hbf + MH;
    u16* ubf = vbf + MV;
    cvt_all<<<2048, 256, 0, stream>>>(H, VT, Uw, hbf);
    gemm256_fused<<<512, 512, 0, stream>>>(hbf, vbf, ubf, Ubp, out);
  } else {
    u16* vbf = (u16*)d_ws;
    u16* ubf = vbf + MV;
    u16* lat = ubf + MU;
    cvt_f32_bf16<<<512, 256, 0, stream>>>(VT, vbf, MV / 8);
    cvt_f32_bf16<<<128, 256, 0, stream>>>(Uw, ubf, MU / 8);
    gemm1_f32<<<2048, 256, 0, stream>>>(H, vbf, lat);
    stage2<<<dim3(128, 32), 256, 0, stream>>>(lat, ubf, Ubp, out);
  }
}